// Round 3
// baseline (37.404 us; speedup 1.0000x reference)
//
#include <hip/hip_runtime.h>

#define BB 32
#define RR 56
#define CC 56
#define CHG 64                       // float4 channel groups (256/4)
#define TPC 4                        // cols per wave tile
#define TPR 4                        // rows per wave tile
#define CSEG (CC / TPC)              // 14
#define RSEG (RR / TPR)              // 14
#define SEGS (BB * RSEG * CSEG)      // 6272 wave tiles
#define NBLK (SEGS / 4)              // 1568 blocks, % 8 == 0

__device__ __forceinline__ void load_row(float4 dst[6], const float4* __restrict__ xv, int base) {
    #pragma unroll
    for (int j = 0; j < 6; ++j) dst[j] = xv[base + j * CHG];
}

__device__ __forceinline__ void load_row_guarded(float4 dst[6], const float4* __restrict__ xv,
                                                 int b, int r, int c0, int lane) {
    const bool rok = (r >= 0) & (r < RR);
    const int base = ((b * RR + r) * CC + c0 - 1) * CHG + lane;
    #pragma unroll
    for (int j = 0; j < 6; ++j) {
        const int cc = c0 - 1 + j;
        float4 v = make_float4(0.f, 0.f, 0.f, 0.f);
        if (rok && cc >= 0 && cc < CC) v = xv[base + j * CHG];
        dst[j] = v;
    }
}

// acc = mid[p+1] + sum of 8 taps (center masked); one output row of 4 pixels.
__device__ __forceinline__ void compute_store(float4* __restrict__ ov, int obase,
                                              const float4 kt[9],
                                              const float4 up[6], const float4 mid[6],
                                              const float4 dn[6]) {
    #pragma unroll
    for (int p = 0; p < TPC; ++p) {
        float4 acc = mid[p + 1];
        #pragma unroll
        for (int dc = 0; dc < 3; ++dc) {
            const float4 ku = kt[dc];
            const float4 xu = up[p + dc];
            acc.x += ku.x * xu.x; acc.y += ku.y * xu.y;
            acc.z += ku.z * xu.z; acc.w += ku.w * xu.w;
        }
        {   // mid row: dc = 0 and 2 only (center tap masked)
            const float4 k0 = kt[3], k2 = kt[5];
            const float4 x0 = mid[p], x2 = mid[p + 2];
            acc.x += k0.x * x0.x + k2.x * x2.x;
            acc.y += k0.y * x0.y + k2.y * x2.y;
            acc.z += k0.z * x0.z + k2.z * x2.z;
            acc.w += k0.w * x0.w + k2.w * x2.w;
        }
        #pragma unroll
        for (int dc = 0; dc < 3; ++dc) {
            const float4 kd = kt[6 + dc];
            const float4 xd = dn[p + dc];
            acc.x += kd.x * xd.x; acc.y += kd.y * xd.y;
            acc.z += kd.z * xd.z; acc.w += kd.w * xd.w;
        }
        ov[obase + p * CHG] = acc;
    }
}

__global__ __launch_bounds__(256) void dwconv3x3_res3(
    const float4* __restrict__ xv,
    const float4* __restrict__ kv,
    float4* __restrict__ ov)
{
    // XCD-chunked swizzle: each XCD gets 784 contiguous tiles = 4 whole images.
    const int bid = (int)blockIdx.x;
    const int swz = (bid & 7) * (NBLK / 8) + (bid >> 3);
    const int tid = swz * 256 + (int)threadIdx.x;
    const int seg = tid >> 6;
    const int lane = tid & 63;

    const int b   = seg / (RSEG * CSEG);
    const int rem = seg - b * (RSEG * CSEG);
    const int rs  = rem / CSEG;
    const int cs  = rem - rs * CSEG;
    const int r0  = rs * TPR;
    const int c0  = cs * TPC;

    // taps (kt[4] = center, unused)
    float4 kt[9];
    #pragma unroll
    for (int t = 0; t < 9; ++t)
        if (t != 4) kt[t] = kv[t * CHG + lane];

    const int ibase = (b * RR + r0) * CC + c0;   // pixel index of tile origin
    const int rowstride = CC * CHG;
    const int obase = ibase * CHG + lane;

    float4 buf0[6], buf1[6], buf2[6], buf3[6];

    const bool interior = (rs > 0) & (rs < RSEG - 1) & (cs > 0) & (cs < CSEG - 1);

    if (interior) {   // wave-uniform branch
        const int bm1 = (ibase - CC - 1) * CHG + lane;  // (r0-1, c0-1)
        load_row(buf0, xv, bm1);                  // r0-1
        load_row(buf1, xv, bm1 + rowstride);      // r0
        load_row(buf2, xv, bm1 + 2 * rowstride);  // r0+1
        load_row(buf3, xv, bm1 + 3 * rowstride);  // r0+2 (prefetch)
        compute_store(ov, obase,                kt, buf0, buf1, buf2);  // out r0
        load_row(buf0, xv, bm1 + 4 * rowstride); // r0+3 (prefetch)
        compute_store(ov, obase + rowstride,    kt, buf1, buf2, buf3);  // out r0+1
        load_row(buf1, xv, bm1 + 5 * rowstride); // r0+4 (prefetch)
        compute_store(ov, obase + 2 * rowstride, kt, buf2, buf3, buf0); // out r0+2
        compute_store(ov, obase + 3 * rowstride, kt, buf3, buf0, buf1); // out r0+3
    } else {
        load_row_guarded(buf0, xv, b, r0 - 1, c0, lane);
        load_row_guarded(buf1, xv, b, r0,     c0, lane);
        load_row_guarded(buf2, xv, b, r0 + 1, c0, lane);
        load_row_guarded(buf3, xv, b, r0 + 2, c0, lane);
        compute_store(ov, obase,                kt, buf0, buf1, buf2);
        load_row_guarded(buf0, xv, b, r0 + 3, c0, lane);
        compute_store(ov, obase + rowstride,    kt, buf1, buf2, buf3);
        load_row_guarded(buf1, xv, b, r0 + 4, c0, lane);
        compute_store(ov, obase + 2 * rowstride, kt, buf2, buf3, buf0);
        compute_store(ov, obase + 3 * rowstride, kt, buf3, buf0, buf1);
    }
}

extern "C" void kernel_launch(void* const* d_in, const int* in_sizes, int n_in,
                              void* d_out, int out_size, void* d_ws, size_t ws_size,
                              hipStream_t stream)
{
    const float4* xv = (const float4*)d_in[0];
    const float4* kv = (const float4*)d_in[1];
    float4* ov       = (float4*)d_out;

    dwconv3x3_res3<<<NBLK, 256, 0, stream>>>(xv, kv, ov);
}

// Round 5
// 34.854 us; speedup vs baseline: 1.0732x; 1.0732x over previous
//
#include <hip/hip_runtime.h>

#define BB 32
#define RR 56
#define CC 56
#define CHG 64                      // channel float4-groups (256/4)
#define TP 4                        // output pixels per thread (along C)
#define SEGS (BB * RR * (CC / TP))  // 25088 wave-segments
#define NBLK (SEGS / 4)             // 6272 blocks (4 waves each), % 8 == 0

typedef float nf4 __attribute__((ext_vector_type(4)));  // native vec for nontemporal builtin

// One wave per 4-pixel row segment; lane = channel group. Each thread loads a
// 3x6 float4 neighborhood once and produces 4 outputs from registers.
// Output stores are non-temporal: out is never re-read, so keep it out of
// L2/L3 to preserve x's Infinity-Cache residency across graph replays.
__global__ __launch_bounds__(256) void dwconv3x3_res4(
    const float4* __restrict__ xv,
    const float4* __restrict__ kv,
    float4* __restrict__ ov)
{
    const int bid = (int)blockIdx.x;
    const int swz = (bid & 7) * (NBLK / 8) + (bid >> 3);  // XCD-chunked swizzle
    const int tid = swz * 256 + (int)threadIdx.x;
    const int seg = tid >> 6;
    const int lane = tid & 63;

    const int b   = seg / (RR * (CC / TP));
    const int rem = seg - b * (RR * (CC / TP));
    const int r   = rem / (CC / TP);
    const int cs  = rem - r * (CC / TP);
    const int c0  = cs * TP;

    // kernel taps: 3x3 x float4; center (t=4) masked in reference
    float4 kt[9];
    #pragma unroll
    for (int t = 0; t < 9; ++t)
        if (t != 4) kt[t] = kv[t * CHG + lane];

    float4 row[3][TP + 2];
    const int pixbase = (b * RR + r) * CC + c0;

    const bool interior = (r > 0) & (r < RR - 1) & (cs > 0) & (cs < (CC / TP) - 1);
    if (interior) {
        // wave-uniform branch (r, cs identical across lanes)
        #pragma unroll
        for (int dr = 0; dr < 3; ++dr) {
            const int rowbase = (pixbase + (dr - 1) * CC - 1) * CHG + lane;
            #pragma unroll
            for (int j = 0; j < TP + 2; ++j)
                row[dr][j] = xv[rowbase + j * CHG];
        }
    } else {
        #pragma unroll
        for (int dr = 0; dr < 3; ++dr) {
            const int rr2 = r + dr - 1;
            #pragma unroll
            for (int j = 0; j < TP + 2; ++j) {
                const int cc2 = c0 + j - 1;
                float4 v = make_float4(0.f, 0.f, 0.f, 0.f);
                if (rr2 >= 0 && rr2 < RR && cc2 >= 0 && cc2 < CC)
                    v = xv[((b * RR + rr2) * CC + cc2) * CHG + lane];
                row[dr][j] = v;
            }
        }
    }

    #pragma unroll
    for (int p = 0; p < TP; ++p) {
        float4 acc = row[1][p + 1];   // residual (center tap zeroed)
        #pragma unroll
        for (int dr = 0; dr < 3; ++dr) {
            #pragma unroll
            for (int dc = 0; dc < 3; ++dc) {
                if (dr == 1 && dc == 1) continue;
                const float4 kk = kt[dr * 3 + dc];
                const float4 xx = row[dr][p + dc];
                acc.x += kk.x * xx.x;
                acc.y += kk.y * xx.y;
                acc.z += kk.z * xx.z;
                acc.w += kk.w * xx.w;
            }
        }
        nf4 accv = { acc.x, acc.y, acc.z, acc.w };
        __builtin_nontemporal_store(accv, (nf4*)&ov[(pixbase + p) * CHG + lane]);
    }
}

extern "C" void kernel_launch(void* const* d_in, const int* in_sizes, int n_in,
                              void* d_out, int out_size, void* d_ws, size_t ws_size,
                              hipStream_t stream)
{
    const float4* xv = (const float4*)d_in[0];
    const float4* kv = (const float4*)d_in[1];
    float4* ov       = (float4*)d_out;

    dwconv3x3_res4<<<NBLK, 256, 0, stream>>>(xv, kv, ov);
}